// Round 3
// baseline (777.337 us; speedup 1.0000x reference)
//
#include <hip/hip_runtime.h>
#include <math.h>

// ---------------------------------------------------------------------------
// LocalAttention: out = (softmax(mask(Q K^T * s)) V) Wo^T + bo
//   Q = x Wq^T + bq etc.  B=2, N=M=2048, D=1024, H=16, hd=64, window/2=64.
// Round 3: fp32 baseline (resubmit; rounds 0-2 were infra failures).
// GEMM: 128x64 tile / 8x4 micro-tile on vector ALU (no fp32 MFMA on CDNA4).
// ---------------------------------------------------------------------------

#define D_MODEL 1024
#define N_HEADS 16
#define HD      64
#define WHALF   64
#define BATCH   2
#define NQTOK   2048
#define MKTOK   2048

// ---------------- fp32 tiled GEMM:  C[M][1024] = X[M][1024] @ W[1024][1024]^T + bias
// BM=128, BN=64, BK=32, 256 threads, 8x4 micro-tile.
#define GBM 128
#define GBN 64
#define GBK 32
#define GSX 132  // Xs row stride (floats): 528B, 16B-multiple -> aligned b128 reads
#define GSW 68   // Ws row stride

__global__ __launch_bounds__(256)
void proj_gemm(const float* __restrict__ X, const float* __restrict__ W,
               const float* __restrict__ bias, float* __restrict__ C) {
  __shared__ __align__(16) float Xs[GBK][GSX];
  __shared__ __align__(16) float Ws[GBK][GSW];
  const int t   = threadIdx.x;
  const int tx  = t & 15;        // output col group (4 cols)
  const int ty  = t >> 4;        // output row group (8 rows)
  const int row0 = blockIdx.x * GBM;
  const int col0 = blockIdx.y * GBN;

  float acc[8][4] = {};

  for (int kt = 0; kt < D_MODEL / GBK; ++kt) {
    const int kbase = kt * GBK;
    __syncthreads();
    // X tile: 128 rows x 8 float4 = 1024 float4 -> 4 per thread, k-major in LDS
#pragma unroll
    for (int p = 0; p < 4; ++p) {
      const int idx = t + p * 256;
      const int r = idx >> 3;     // 0..127
      const int f = idx & 7;      // float4 index along k
      const float4 v = *(const float4*)(X + (size_t)(row0 + r) * D_MODEL + kbase + f * 4);
      Xs[f * 4 + 0][r] = v.x; Xs[f * 4 + 1][r] = v.y;
      Xs[f * 4 + 2][r] = v.z; Xs[f * 4 + 3][r] = v.w;
    }
    // W tile: 64 rows x 8 float4 = 512 float4 -> 2 per thread
#pragma unroll
    for (int p = 0; p < 2; ++p) {
      const int idx = t + p * 256;
      const int r = idx >> 3;     // 0..63
      const int f = idx & 7;
      const float4 v = *(const float4*)(W + (size_t)(col0 + r) * D_MODEL + kbase + f * 4);
      Ws[f * 4 + 0][r] = v.x; Ws[f * 4 + 1][r] = v.y;
      Ws[f * 4 + 2][r] = v.z; Ws[f * 4 + 3][r] = v.w;
    }
    __syncthreads();
#pragma unroll 4
    for (int kk = 0; kk < GBK; ++kk) {
      const float4 a0 = *(const float4*)&Xs[kk][ty * 8];
      const float4 a1 = *(const float4*)&Xs[kk][ty * 8 + 4];
      const float4 b  = *(const float4*)&Ws[kk][tx * 4];
      const float av[8] = {a0.x, a0.y, a0.z, a0.w, a1.x, a1.y, a1.z, a1.w};
      const float bv[4] = {b.x, b.y, b.z, b.w};
#pragma unroll
      for (int i = 0; i < 8; ++i)
#pragma unroll
        for (int j = 0; j < 4; ++j)
          acc[i][j] = fmaf(av[i], bv[j], acc[i][j]);
    }
  }

  const float4 b4 = *(const float4*)(bias + col0 + tx * 4);
#pragma unroll
  for (int i = 0; i < 8; ++i) {
    float4 o;
    o.x = acc[i][0] + b4.x; o.y = acc[i][1] + b4.y;
    o.z = acc[i][2] + b4.z; o.w = acc[i][3] + b4.w;
    *(float4*)(C + (size_t)(row0 + ty * 8 + i) * D_MODEL + col0 + tx * 4) = o;
  }
}

// ---------------- banded attention ----------------
// One block (256 thr) per (b, h, 32-query tile). Band = 32+128 <= 160 keys,
// processed in 2 chunks of 80 to keep LDS < 64 KB.
#define QB    32
#define CHUNK 80
#define KS    65    // K/V/Q LDS row stride (floats) -> conflict-free scalar reads
#define PS    161   // P row stride

__global__ __launch_bounds__(256)
void local_attn(const float* __restrict__ Q, const float* __restrict__ K,
                const float* __restrict__ V, float* __restrict__ AO) {
  __shared__ float Qs[QB][KS];
  __shared__ float KVs[CHUNK][KS];
  __shared__ float P[QB][PS];
  __shared__ float inv_s[QB];

  const int t = threadIdx.x;
  const int nqb = NQTOK / QB;                 // 64
  const int bid = blockIdx.x;
  const int qb  = bid % nqb;
  const int h   = (bid / nqb) % N_HEADS;
  const int b   = bid / (nqb * N_HEADS);
  const int q0  = qb * QB;
  const int j_lo = max(0, q0 - WHALF);
  const int j_hi = min(MKTOK - 1, q0 + QB - 1 + WHALF);
  const int KB   = j_hi - j_lo + 1;           // 96..160
  const float scale = 0.125f;                 // 1/sqrt(64)

  const float* Qb = Q + (size_t)b * NQTOK * D_MODEL + h * HD;
  const float* Kb = K + (size_t)b * MKTOK * D_MODEL + h * HD;
  const float* Vb = V + (size_t)b * MKTOK * D_MODEL + h * HD;
  float*       Ob = AO + (size_t)b * NQTOK * D_MODEL + h * HD;

  // stage Q (pre-scaled): 32 rows x 16 float4
  for (int idx = t; idx < QB * 16; idx += 256) {
    const int r = idx >> 4, f = idx & 15;
    const float4 v = *(const float4*)(Qb + (size_t)(q0 + r) * D_MODEL + f * 4);
    Qs[r][f * 4 + 0] = v.x * scale; Qs[r][f * 4 + 1] = v.y * scale;
    Qs[r][f * 4 + 2] = v.z * scale; Qs[r][f * 4 + 3] = v.w * scale;
  }

  // ---- logits: P[q][jj] = (Q K^T)*s ----
  const int txk = t & 15;    // 16 key groups x 5 keys = 80 keys/chunk
  const int tyq = t >> 4;    // 16 query groups x 2 queries
  for (int c = 0; c < 2; ++c) {
    const int jc0 = c * CHUNK;
    const int cnt = min(CHUNK, KB - jc0);     // chunk1 may be 16..80
    __syncthreads();                           // Q staged / prev KVs consumed
    for (int idx = t; idx < cnt * 16; idx += 256) {
      const int r = idx >> 4, f = idx & 15;
      const float4 v = *(const float4*)(Kb + (size_t)(j_lo + jc0 + r) * D_MODEL + f * 4);
      KVs[r][f * 4 + 0] = v.x; KVs[r][f * 4 + 1] = v.y;
      KVs[r][f * 4 + 2] = v.z; KVs[r][f * 4 + 3] = v.w;
    }
    __syncthreads();
    float acc[2][5] = {};
#pragma unroll 4
    for (int d = 0; d < HD; ++d) {
      const float q0v = Qs[2 * tyq + 0][d];
      const float q1v = Qs[2 * tyq + 1][d];
#pragma unroll
      for (int kc = 0; kc < 5; ++kc) {
        const float kv = KVs[txk * 5 + kc][d];
        acc[0][kc] = fmaf(q0v, kv, acc[0][kc]);
        acc[1][kc] = fmaf(q1v, kv, acc[1][kc]);
      }
    }
#pragma unroll
    for (int qc = 0; qc < 2; ++qc)
#pragma unroll
      for (int kc = 0; kc < 5; ++kc)
        P[2 * tyq + qc][jc0 + txk * 5 + kc] = acc[qc][kc];
  }
  __syncthreads();

  // ---- masked softmax over each P row (8 threads per row) ----
  {
    const int q = t >> 3, s8 = t & 7;
    const int qi = q0 + q;
    float mx = -1e30f;
    for (int jj = s8; jj < KB; jj += 8) {
      int diff = qi - (j_lo + jj); if (diff < 0) diff = -diff;
      if (diff <= WHALF) mx = fmaxf(mx, P[q][jj]);
    }
    mx = fmaxf(mx, __shfl_xor(mx, 1));
    mx = fmaxf(mx, __shfl_xor(mx, 2));
    mx = fmaxf(mx, __shfl_xor(mx, 4));
    float sum = 0.f;
    for (int jj = s8; jj < KB; jj += 8) {
      int diff = qi - (j_lo + jj); if (diff < 0) diff = -diff;
      float e = 0.f;
      if (diff <= WHALF) { e = expf(P[q][jj] - mx); sum += e; }
      P[q][jj] = e;
    }
    sum += __shfl_xor(sum, 1);
    sum += __shfl_xor(sum, 2);
    sum += __shfl_xor(sum, 4);
    if (s8 == 0) inv_s[q] = 1.f / sum;
  }

  // ---- PV: out[q][d] = sum_j P[q][j] * V[j][d] ----
  const int d  = t & 63;
  const int qg = t >> 6;        // 0..3, 8 queries each
  float oacc[8] = {};
  for (int c = 0; c < 2; ++c) {
    const int jc0 = c * CHUNK;
    const int cnt = min(CHUNK, KB - jc0);
    __syncthreads();            // P final / prev KVs consumed
    for (int idx = t; idx < cnt * 16; idx += 256) {
      const int r = idx >> 4, f = idx & 15;
      const float4 v = *(const float4*)(Vb + (size_t)(j_lo + jc0 + r) * D_MODEL + f * 4);
      KVs[r][f * 4 + 0] = v.x; KVs[r][f * 4 + 1] = v.y;
      KVs[r][f * 4 + 2] = v.z; KVs[r][f * 4 + 3] = v.w;
    }
    __syncthreads();
    for (int jj = 0; jj < cnt; ++jj) {
      const float v = KVs[jj][d];
#pragma unroll
      for (int i = 0; i < 8; ++i)
        oacc[i] = fmaf(P[qg * 8 + i][jc0 + jj], v, oacc[i]);
    }
  }
#pragma unroll
  for (int i = 0; i < 8; ++i) {
    const int q = qg * 8 + i;
    Ob[(size_t)(q0 + q) * D_MODEL + d] = oacc[i] * inv_s[q];
  }
}

// ---------------------------------------------------------------------------
extern "C" void kernel_launch(void* const* d_in, const int* in_sizes, int n_in,
                              void* d_out, int out_size, void* d_ws, size_t ws_size,
                              hipStream_t stream) {
  const float* queries = (const float*)d_in[0];
  const float* keys    = (const float*)d_in[1];
  const float* values  = (const float*)d_in[2];
  const float* wq = (const float*)d_in[3];
  const float* bq = (const float*)d_in[4];
  const float* wk = (const float*)d_in[5];
  const float* bk = (const float*)d_in[6];
  const float* wv = (const float*)d_in[7];
  const float* bv = (const float*)d_in[8];
  const float* wo = (const float*)d_in[9];
  const float* bo = (const float*)d_in[10];
  float* out = (float*)d_out;

  const int Mrows = BATCH * NQTOK;                 // 4096
  const size_t mat = (size_t)Mrows * D_MODEL;      // 4.19M floats
  float* Qws = (float*)d_ws;
  float* Kws = Qws + mat;
  float* Vws = Kws + mat;
  // AO aliases Qws: each attention block stages its Q slice into LDS before
  // writing AO to exactly that (row, head-column) slice, barrier-separated;
  // other blocks never read that slice -> safe, saves 16MB of ws.
  float* AOws = Qws;

  dim3 gg(Mrows / GBM, D_MODEL / GBN);             // 32 x 16 = 512 blocks
  proj_gemm<<<gg, 256, 0, stream>>>(queries, wq, bq, Qws);
  proj_gemm<<<gg, 256, 0, stream>>>(keys,    wk, bk, Kws);
  proj_gemm<<<gg, 256, 0, stream>>>(values,  wv, bv, Vws);

  local_attn<<<dim3(BATCH * N_HEADS * (NQTOK / QB)), 256, 0, stream>>>(Qws, Kws, Vws, AOws);

  proj_gemm<<<gg, 256, 0, stream>>>(AOws, wo, bo, out);
}

// Round 5
// 362.164 us; speedup vs baseline: 2.1464x; 2.1464x over previous
//
#include <hip/hip_runtime.h>
#include <math.h>

// ---------------------------------------------------------------------------
// LocalAttention. Round 5 (= round-4 resubmit; infra failure, never ran):
// projections via split-bf16 MFMA (3-MFMA trick, fp32-grade accuracy) when
// ws_size allows; round-3-verified fp32 VALU fallback otherwise.
// ---------------------------------------------------------------------------

#define D_MODEL 1024
#define N_HEADS 16
#define HD      64
#define WHALF   64
#define BATCH   2
#define NQTOK   2048
#define MKTOK   2048

typedef float f32x4 __attribute__((ext_vector_type(4)));
typedef short s16x8 __attribute__((ext_vector_type(8)));

static __device__ __forceinline__ unsigned short f2bf(float x) {
  unsigned u = __float_as_uint(x);
  unsigned r = (u + 0x7fffu + ((u >> 16) & 1u)) >> 16;   // RTNE
  return (unsigned short)r;
}
static __device__ __forceinline__ float bf2f(unsigned short h) {
  return __uint_as_float(((unsigned)h) << 16);
}

// ---------------- fp32 -> (bf16 hi, bf16 lo) split, 8 elements/thread -------
__global__ __launch_bounds__(256)
void cvt_split(const float* __restrict__ in, unsigned short* __restrict__ hi,
               unsigned short* __restrict__ lo, int ngroups) {
  const int g = blockIdx.x * 256 + threadIdx.x;
  if (g >= ngroups) return;
  const float4 v0 = *(const float4*)(in + (size_t)g * 8);
  const float4 v1 = *(const float4*)(in + (size_t)g * 8 + 4);
  const float xs[8] = {v0.x, v0.y, v0.z, v0.w, v1.x, v1.y, v1.z, v1.w};
  unsigned short hs[8], ls[8];
#pragma unroll
  for (int i = 0; i < 8; ++i) {
    hs[i] = f2bf(xs[i]);
    ls[i] = f2bf(xs[i] - bf2f(hs[i]));
  }
  uint4 hv, lv;
  hv.x = (unsigned)hs[0] | ((unsigned)hs[1] << 16);
  hv.y = (unsigned)hs[2] | ((unsigned)hs[3] << 16);
  hv.z = (unsigned)hs[4] | ((unsigned)hs[5] << 16);
  hv.w = (unsigned)hs[6] | ((unsigned)hs[7] << 16);
  lv.x = (unsigned)ls[0] | ((unsigned)ls[1] << 16);
  lv.y = (unsigned)ls[2] | ((unsigned)ls[3] << 16);
  lv.z = (unsigned)ls[4] | ((unsigned)ls[5] << 16);
  lv.w = (unsigned)ls[6] | ((unsigned)ls[7] << 16);
  *(uint4*)(hi + (size_t)g * 8) = hv;
  *(uint4*)(lo + (size_t)g * 8) = lv;
}

// ---------------- split-bf16 MFMA GEMM: C[M][1024] = A @ B^T + bias ---------
// A as hi/lo bf16 [M][1024], B as hi/lo bf16 [1024][1024] (n-major, k contig).
// BM=128, BN=64, BK=32, 256 threads (4 waves as 2x2), wave tile 64x32.
#define TBM 128
#define TBN 64
#define TBK 32
// LDS (ushort idx): Ahi @0 (128x32), Alo @4096, Bhi @8192 (64x32), Blo @10240.

__global__ __launch_bounds__(256)
void mfma_gemm(const unsigned short* __restrict__ Ah, const unsigned short* __restrict__ Al,
               const unsigned short* __restrict__ Bh, const unsigned short* __restrict__ Bl,
               const float* __restrict__ bias, float* __restrict__ C) {
  __shared__ unsigned short smem[12288];           // 24 KB
  const int t  = threadIdx.x;
  const int wv = t >> 6;
  const int ln = t & 63;
  const int row0 = blockIdx.x * TBM;
  const int col0 = blockIdx.y * TBN;
  const int wr = wv >> 1, wc = wv & 1;

  f32x4 acc[4][2];
#pragma unroll
  for (int mi = 0; mi < 4; ++mi)
#pragma unroll
    for (int ni = 0; ni < 2; ++ni)
      acc[mi][ni] = (f32x4){0.f, 0.f, 0.f, 0.f};

  auto lds3 = (__attribute__((address_space(3))) unsigned short*)smem;

  for (int kt = 0; kt < D_MODEL / TBK; ++kt) {
    const int kb = kt * TBK;
    if (kt) __syncthreads();                       // prev compute done
    // stage 24 x 1KB chunks via global_load_lds (16B/lane), 6 per wave
#pragma unroll
    for (int cc = 0; cc < 6; ++cc) {
      const int c = wv * 6 + cc;
      const unsigned short* src;
      int dst, rowg;
      if (c < 8)       { src = Ah; dst = c * 512;              rowg = row0 + c * 16; }
      else if (c < 16) { src = Al; dst = 4096 + (c - 8) * 512; rowg = row0 + (c - 8) * 16; }
      else if (c < 20) { src = Bh; dst = 8192 + (c - 16) * 512; rowg = col0 + (c - 16) * 16; }
      else             { src = Bl; dst = 10240 + (c - 20) * 512; rowg = col0 + (c - 20) * 16; }
      const unsigned short* g =
          src + (size_t)(rowg + (ln >> 2)) * D_MODEL + kb + (ln & 3) * 8;
      __builtin_amdgcn_global_load_lds((const __attribute__((address_space(1))) void*)g,
                                       (__attribute__((address_space(3))) void*)(lds3 + dst),
                                       16, 0, 0);
    }
    __syncthreads();                               // drains vmcnt, data visible

    const int fr = ln & 15;
    const int ks = (ln >> 4) * 8;
    s16x8 a_h[4], a_l[4], b_h[2], b_l[2];
#pragma unroll
    for (int mi = 0; mi < 4; ++mi) {
      const int r = wr * 64 + mi * 16 + fr;
      a_h[mi] = *(const s16x8*)&smem[r * 32 + ks];
      a_l[mi] = *(const s16x8*)&smem[4096 + r * 32 + ks];
    }
#pragma unroll
    for (int ni = 0; ni < 2; ++ni) {
      const int r = wc * 32 + ni * 16 + fr;
      b_h[ni] = *(const s16x8*)&smem[8192 + r * 32 + ks];
      b_l[ni] = *(const s16x8*)&smem[10240 + r * 32 + ks];
    }
#pragma unroll
    for (int mi = 0; mi < 4; ++mi)
#pragma unroll
      for (int ni = 0; ni < 2; ++ni) {
        acc[mi][ni] = __builtin_amdgcn_mfma_f32_16x16x32_bf16(a_h[mi], b_h[ni], acc[mi][ni], 0, 0, 0);
        acc[mi][ni] = __builtin_amdgcn_mfma_f32_16x16x32_bf16(a_h[mi], b_l[ni], acc[mi][ni], 0, 0, 0);
        acc[mi][ni] = __builtin_amdgcn_mfma_f32_16x16x32_bf16(a_l[mi], b_h[ni], acc[mi][ni], 0, 0, 0);
      }
  }

  // epilogue: C/D layout col = lane&15, row = (lane>>4)*4 + reg  [m89-verified]
  const int fr = ln & 15, fq = ln >> 4;
  float bval[2];
  bval[0] = bias[col0 + wc * 32 + fr];
  bval[1] = bias[col0 + wc * 32 + 16 + fr];
#pragma unroll
  for (int mi = 0; mi < 4; ++mi)
#pragma unroll
    for (int ni = 0; ni < 2; ++ni)
#pragma unroll
      for (int j = 0; j < 4; ++j) {
        const int r = row0 + wr * 64 + mi * 16 + fq * 4 + j;
        const int cg = col0 + wc * 32 + ni * 16 + fr;
        C[(size_t)r * D_MODEL + cg] = acc[mi][ni][j] + bval[ni];
      }
}

// ---------------- fp32 tiled GEMM (fallback path) ---------------------------
#define GBM 128
#define GBN 64
#define GBK 32
#define GSX 132
#define GSW 68

__global__ __launch_bounds__(256)
void proj_gemm(const float* __restrict__ X, const float* __restrict__ W,
               const float* __restrict__ bias, float* __restrict__ C) {
  __shared__ __align__(16) float Xs[GBK][GSX];
  __shared__ __align__(16) float Ws[GBK][GSW];
  const int t   = threadIdx.x;
  const int tx  = t & 15;
  const int ty  = t >> 4;
  const int row0 = blockIdx.x * GBM;
  const int col0 = blockIdx.y * GBN;
  float acc[8][4] = {};
  for (int kt = 0; kt < D_MODEL / GBK; ++kt) {
    const int kbase = kt * GBK;
    __syncthreads();
#pragma unroll
    for (int p = 0; p < 4; ++p) {
      const int idx = t + p * 256;
      const int r = idx >> 3, f = idx & 7;
      const float4 v = *(const float4*)(X + (size_t)(row0 + r) * D_MODEL + kbase + f * 4);
      Xs[f * 4 + 0][r] = v.x; Xs[f * 4 + 1][r] = v.y;
      Xs[f * 4 + 2][r] = v.z; Xs[f * 4 + 3][r] = v.w;
    }
#pragma unroll
    for (int p = 0; p < 2; ++p) {
      const int idx = t + p * 256;
      const int r = idx >> 3, f = idx & 7;
      const float4 v = *(const float4*)(W + (size_t)(col0 + r) * D_MODEL + kbase + f * 4);
      Ws[f * 4 + 0][r] = v.x; Ws[f * 4 + 1][r] = v.y;
      Ws[f * 4 + 2][r] = v.z; Ws[f * 4 + 3][r] = v.w;
    }
    __syncthreads();
#pragma unroll 4
    for (int kk = 0; kk < GBK; ++kk) {
      const float4 a0 = *(const float4*)&Xs[kk][ty * 8];
      const float4 a1 = *(const float4*)&Xs[kk][ty * 8 + 4];
      const float4 b  = *(const float4*)&Ws[kk][tx * 4];
      const float av[8] = {a0.x, a0.y, a0.z, a0.w, a1.x, a1.y, a1.z, a1.w};
      const float bv[4] = {b.x, b.y, b.z, b.w};
#pragma unroll
      for (int i = 0; i < 8; ++i)
#pragma unroll
        for (int j = 0; j < 4; ++j)
          acc[i][j] = fmaf(av[i], bv[j], acc[i][j]);
    }
  }
  const float4 b4 = *(const float4*)(bias + col0 + tx * 4);
#pragma unroll
  for (int i = 0; i < 8; ++i) {
    float4 o;
    o.x = acc[i][0] + b4.x; o.y = acc[i][1] + b4.y;
    o.z = acc[i][2] + b4.z; o.w = acc[i][3] + b4.w;
    *(float4*)(C + (size_t)(row0 + ty * 8 + i) * D_MODEL + col0 + tx * 4) = o;
  }
}

// ---------------- banded attention ----------------
#define QB    32
#define CHUNK 80
#define KS    65
#define PS    161

__global__ __launch_bounds__(256)
void local_attn(const float* __restrict__ Q, const float* __restrict__ K,
                const float* __restrict__ V, float* __restrict__ AO,
                unsigned short* __restrict__ AOh, unsigned short* __restrict__ AOl,
                int split_out) {
  __shared__ float Qs[QB][KS];
  __shared__ float KVs[CHUNK][KS];
  __shared__ float P[QB][PS];
  __shared__ float inv_s[QB];

  const int t = threadIdx.x;
  const int nqb = NQTOK / QB;
  const int bid = blockIdx.x;
  const int qb  = bid % nqb;
  const int h   = (bid / nqb) % N_HEADS;
  const int b   = bid / (nqb * N_HEADS);
  const int q0  = qb * QB;
  const int j_lo = max(0, q0 - WHALF);
  const int j_hi = min(MKTOK - 1, q0 + QB - 1 + WHALF);
  const int KB   = j_hi - j_lo + 1;
  const float scale = 0.125f;

  const size_t base = (size_t)b * NQTOK * D_MODEL + h * HD;
  const float* Qb = Q + base;
  const float* Kb = K + base;
  const float* Vb = V + base;

  for (int idx = t; idx < QB * 16; idx += 256) {
    const int r = idx >> 4, f = idx & 15;
    const float4 v = *(const float4*)(Qb + (size_t)(q0 + r) * D_MODEL + f * 4);
    Qs[r][f * 4 + 0] = v.x * scale; Qs[r][f * 4 + 1] = v.y * scale;
    Qs[r][f * 4 + 2] = v.z * scale; Qs[r][f * 4 + 3] = v.w * scale;
  }

  const int txk = t & 15;
  const int tyq = t >> 4;
  for (int c = 0; c < 2; ++c) {
    const int jc0 = c * CHUNK;
    const int cnt = min(CHUNK, KB - jc0);
    __syncthreads();
    for (int idx = t; idx < cnt * 16; idx += 256) {
      const int r = idx >> 4, f = idx & 15;
      const float4 v = *(const float4*)(Kb + (size_t)(j_lo + jc0 + r) * D_MODEL + f * 4);
      KVs[r][f * 4 + 0] = v.x; KVs[r][f * 4 + 1] = v.y;
      KVs[r][f * 4 + 2] = v.z; KVs[r][f * 4 + 3] = v.w;
    }
    __syncthreads();
    float acc[2][5] = {};
#pragma unroll 4
    for (int d = 0; d < HD; ++d) {
      const float q0v = Qs[2 * tyq + 0][d];
      const float q1v = Qs[2 * tyq + 1][d];
#pragma unroll
      for (int kc = 0; kc < 5; ++kc) {
        const float kv = KVs[txk * 5 + kc][d];
        acc[0][kc] = fmaf(q0v, kv, acc[0][kc]);
        acc[1][kc] = fmaf(q1v, kv, acc[1][kc]);
      }
    }
#pragma unroll
    for (int qc = 0; qc < 2; ++qc)
#pragma unroll
      for (int kc = 0; kc < 5; ++kc)
        P[2 * tyq + qc][jc0 + txk * 5 + kc] = acc[qc][kc];
  }
  __syncthreads();

  {
    const int q = t >> 3, s8 = t & 7;
    const int qi = q0 + q;
    float mx = -1e30f;
    for (int jj = s8; jj < KB; jj += 8) {
      int diff = qi - (j_lo + jj); if (diff < 0) diff = -diff;
      if (diff <= WHALF) mx = fmaxf(mx, P[q][jj]);
    }
    mx = fmaxf(mx, __shfl_xor(mx, 1));
    mx = fmaxf(mx, __shfl_xor(mx, 2));
    mx = fmaxf(mx, __shfl_xor(mx, 4));
    float sum = 0.f;
    for (int jj = s8; jj < KB; jj += 8) {
      int diff = qi - (j_lo + jj); if (diff < 0) diff = -diff;
      float e = 0.f;
      if (diff <= WHALF) { e = expf(P[q][jj] - mx); sum += e; }
      P[q][jj] = e;
    }
    sum += __shfl_xor(sum, 1);
    sum += __shfl_xor(sum, 2);
    sum += __shfl_xor(sum, 4);
    if (s8 == 0) inv_s[q] = 1.f / sum;
  }

  const int d  = t & 63;
  const int qg = t >> 6;
  float oacc[8] = {};
  for (int c = 0; c < 2; ++c) {
    const int jc0 = c * CHUNK;
    const int cnt = min(CHUNK, KB - jc0);
    __syncthreads();
    for (int idx = t; idx < cnt * 16; idx += 256) {
      const int r = idx >> 4, f = idx & 15;
      const float4 v = *(const float4*)(Vb + (size_t)(j_lo + jc0 + r) * D_MODEL + f * 4);
      KVs[r][f * 4 + 0] = v.x; KVs[r][f * 4 + 1] = v.y;
      KVs[r][f * 4 + 2] = v.z; KVs[r][f * 4 + 3] = v.w;
    }
    __syncthreads();
    for (int jj = 0; jj < cnt; ++jj) {
      const float v = KVs[jj][d];
#pragma unroll
      for (int i = 0; i < 8; ++i)
        oacc[i] = fmaf(P[qg * 8 + i][jc0 + jj], v, oacc[i]);
    }
  }
#pragma unroll
  for (int i = 0; i < 8; ++i) {
    const int q = qg * 8 + i;
    const float o = oacc[i] * inv_s[q];
    const size_t off = base + (size_t)(q0 + q) * D_MODEL + d;
    if (split_out) {
      const unsigned short hh = f2bf(o);
      AOh[off] = hh;
      AOl[off] = f2bf(o - bf2f(hh));
    } else {
      AO[off] = o;
    }
  }
}

// ---------------------------------------------------------------------------
extern "C" void kernel_launch(void* const* d_in, const int* in_sizes, int n_in,
                              void* d_out, int out_size, void* d_ws, size_t ws_size,
                              hipStream_t stream) {
  const float* queries = (const float*)d_in[0];
  const float* keys    = (const float*)d_in[1];
  const float* values  = (const float*)d_in[2];
  const float* wq = (const float*)d_in[3];
  const float* bq = (const float*)d_in[4];
  const float* wk = (const float*)d_in[5];
  const float* bk = (const float*)d_in[6];
  const float* wv = (const float*)d_in[7];
  const float* bv = (const float*)d_in[8];
  const float* wo = (const float*)d_in[9];
  const float* bo = (const float*)d_in[10];
  float* out = (float*)d_out;

  const size_t mat  = (size_t)BATCH * NQTOK * D_MODEL;   // 4,194,304
  const size_t wmat = (size_t)D_MODEL * D_MODEL;         // 1,048,576
  const size_t need = 6 * mat * 2 + 8 * wmat * 2 + 3 * mat * 4;  // 117,440,512

  const dim3 attn_grid(BATCH * N_HEADS * (NQTOK / QB));

  if (ws_size >= need) {
    // ---- split-bf16 MFMA path ----
    unsigned short* qh  = (unsigned short*)d_ws;
    unsigned short* ql  = qh + mat;
    unsigned short* kh  = ql + mat;
    unsigned short* kl  = kh + mat;
    unsigned short* vh  = kl + mat;
    unsigned short* vl  = vh + mat;
    unsigned short* wqh = vl + mat;
    unsigned short* wql = wqh + wmat;
    unsigned short* wkh = wql + wmat;
    unsigned short* wkl = wkh + wmat;
    unsigned short* wvh = wkl + wmat;
    unsigned short* wvl = wvh + wmat;
    unsigned short* woh = wvl + wmat;
    unsigned short* wol = woh + wmat;
    float* Qf = (float*)(wol + wmat);
    float* Kf = Qf + mat;
    float* Vf = Kf + mat;
    unsigned short* aoh = qh;   // alias: q-conv buffers dead after Q GEMM
    unsigned short* aol = ql;

    cvt_split<<<dim3((unsigned)(mat / 2048)), 256, 0, stream>>>(queries, qh, ql, (int)(mat / 8));
    cvt_split<<<dim3((unsigned)(mat / 2048)), 256, 0, stream>>>(keys,    kh, kl, (int)(mat / 8));
    cvt_split<<<dim3((unsigned)(mat / 2048)), 256, 0, stream>>>(values,  vh, vl, (int)(mat / 8));
    cvt_split<<<dim3((unsigned)(wmat / 2048)), 256, 0, stream>>>(wq, wqh, wql, (int)(wmat / 8));
    cvt_split<<<dim3((unsigned)(wmat / 2048)), 256, 0, stream>>>(wk, wkh, wkl, (int)(wmat / 8));
    cvt_split<<<dim3((unsigned)(wmat / 2048)), 256, 0, stream>>>(wv, wvh, wvl, (int)(wmat / 8));
    cvt_split<<<dim3((unsigned)(wmat / 2048)), 256, 0, stream>>>(wo, woh, wol, (int)(wmat / 8));

    const dim3 gm(BATCH * NQTOK / TBM, D_MODEL / TBN);   // 32 x 16
    mfma_gemm<<<gm, 256, 0, stream>>>(qh, ql, wqh, wql, bq, Qf);
    mfma_gemm<<<gm, 256, 0, stream>>>(kh, kl, wkh, wkl, bk, Kf);
    mfma_gemm<<<gm, 256, 0, stream>>>(vh, vl, wvh, wvl, bv, Vf);

    local_attn<<<attn_grid, 256, 0, stream>>>(Qf, Kf, Vf, nullptr, aoh, aol, 1);

    mfma_gemm<<<gm, 256, 0, stream>>>(aoh, aol, woh, wol, bo, out);
  } else {
    // ---- fp32 fallback (round-3 verified) ----
    float* Qws = (float*)d_ws;
    float* Kws = Qws + mat;
    float* Vws = Kws + mat;
    float* AOws = Qws;   // alias, barrier-separated per-block slice

    const dim3 gg(BATCH * NQTOK / GBM, D_MODEL / GBN);
    proj_gemm<<<gg, 256, 0, stream>>>(queries, wq, bq, Qws);
    proj_gemm<<<gg, 256, 0, stream>>>(keys,    wk, bk, Kws);
    proj_gemm<<<gg, 256, 0, stream>>>(values,  wv, bv, Vws);
    local_attn<<<attn_grid, 256, 0, stream>>>(Qws, Kws, Vws, AOws, nullptr, nullptr, 0);
    proj_gemm<<<gg, 256, 0, stream>>>(AOws, wo, bo, out);
  }
}

// Round 10
// 301.517 us; speedup vs baseline: 2.5781x; 1.2011x over previous
//
#include <hip/hip_runtime.h>
#include <math.h>

// ---------------------------------------------------------------------------
// LocalAttention. Round 10 (= round-6..9 resubmit; infra failures, never ran):
// MFMA everywhere. Projections split-bf16 MFMA (fp32-grade); attention
// QK^T+PV also split-bf16 MFMA with in-register softmax; V produced
// pre-transposed by its projection GEMM epilogue. fp32 fallback if ws small.
// ---------------------------------------------------------------------------

#define D_MODEL 1024
#define N_HEADS 16
#define HD      64
#define WHALF   64
#define BATCH   2
#define NQTOK   2048
#define MKTOK   2048

typedef float f32x4 __attribute__((ext_vector_type(4)));
typedef short s16x8 __attribute__((ext_vector_type(8)));
typedef unsigned short u16;

static __device__ __forceinline__ u16 f2bf(float x) {
  unsigned u = __float_as_uint(x);
  unsigned r = (u + 0x7fffu + ((u >> 16) & 1u)) >> 16;   // RTNE
  return (u16)r;
}
static __device__ __forceinline__ float bf2f(u16 h) {
  return __uint_as_float(((unsigned)h) << 16);
}

// ---------------- fused fp32 -> (bf16 hi, bf16 lo) for all 7 inputs --------
// groups of 8 elems. Regions: q,k,v (524288 groups each), wq,wk,wv,wo (131072).
#define MAT  4194304u
#define WMAT 1048576u

__global__ __launch_bounds__(256)
void cvt_all(const float* __restrict__ q, const float* __restrict__ k,
             const float* __restrict__ v, const float* __restrict__ wq,
             const float* __restrict__ wk, const float* __restrict__ wv,
             const float* __restrict__ wo, u16* __restrict__ W) {
  const unsigned g = blockIdx.x * 256 + threadIdx.x;  // 0 .. 2097151
  const float* src;
  size_t dbase; unsigned off;
  if (g < 524288u)        { src = q;  dbase = 0;                  off = g; }
  else if (g < 1048576u)  { src = k;  dbase = 2u * MAT;           off = g - 524288u; }
  else if (g < 1572864u)  { src = v;  dbase = 4u * MAT;           off = g - 1048576u; }
  else if (g < 1703936u)  { src = wq; dbase = 6u * (size_t)MAT;               off = g - 1572864u; }
  else if (g < 1835008u)  { src = wk; dbase = 6u * (size_t)MAT + 2u * WMAT;   off = g - 1703936u; }
  else if (g < 1966080u)  { src = wv; dbase = 6u * (size_t)MAT + 4u * WMAT;   off = g - 1835008u; }
  else                    { src = wo; dbase = 6u * (size_t)MAT + 6u * WMAT;   off = g - 1966080u; }
  const size_t stride = (dbase < 6u * (size_t)MAT) ? MAT : WMAT;   // hi->lo distance
  u16* dh = W + dbase;
  u16* dl = dh + stride;
  const size_t e = (size_t)off * 8;
  const float4 v0 = *(const float4*)(src + e);
  const float4 v1 = *(const float4*)(src + e + 4);
  const float xs[8] = {v0.x, v0.y, v0.z, v0.w, v1.x, v1.y, v1.z, v1.w};
  u16 hs[8], ls[8];
#pragma unroll
  for (int i = 0; i < 8; ++i) {
    hs[i] = f2bf(xs[i]);
    ls[i] = f2bf(xs[i] - bf2f(hs[i]));
  }
  uint4 hv, lv;
  hv.x = hs[0] | ((unsigned)hs[1] << 16); hv.y = hs[2] | ((unsigned)hs[3] << 16);
  hv.z = hs[4] | ((unsigned)hs[5] << 16); hv.w = hs[6] | ((unsigned)hs[7] << 16);
  lv.x = ls[0] | ((unsigned)ls[1] << 16); lv.y = ls[2] | ((unsigned)ls[3] << 16);
  lv.z = ls[4] | ((unsigned)ls[5] << 16); lv.w = ls[6] | ((unsigned)ls[7] << 16);
  *(uint4*)(dh + e) = hv;
  *(uint4*)(dl + e) = lv;
}

// ---------------- split-bf16 MFMA GEMM: C[M][1024] = A @ B^T + bias ---------
// mode 0: fp32 out. mode 1: bf16 hi/lo out. mode 2: bf16 hi/lo TRANSPOSED
// (per batch: Ct[b][col][tok]) for the V projection.
#define TBM 128
#define TBN 64
#define TBK 32

__global__ __launch_bounds__(256)
void mfma_gemm(const u16* __restrict__ Ah, const u16* __restrict__ Al,
               const u16* __restrict__ Bh, const u16* __restrict__ Bl,
               const float* __restrict__ bias, float* __restrict__ Cf,
               u16* __restrict__ Ch, u16* __restrict__ Cl, int mode) {
  __shared__ u16 smem[12288];           // 24 KB
  const int t  = threadIdx.x;
  const int wv = t >> 6;
  const int ln = t & 63;
  const int row0 = blockIdx.x * TBM;
  const int col0 = blockIdx.y * TBN;
  const int wr = wv >> 1, wc = wv & 1;

  f32x4 acc[4][2];
#pragma unroll
  for (int mi = 0; mi < 4; ++mi)
#pragma unroll
    for (int ni = 0; ni < 2; ++ni)
      acc[mi][ni] = (f32x4){0.f, 0.f, 0.f, 0.f};

  auto lds3 = (__attribute__((address_space(3))) u16*)smem;

  for (int kt = 0; kt < D_MODEL / TBK; ++kt) {
    const int kb = kt * TBK;
    if (kt) __syncthreads();
#pragma unroll
    for (int cc = 0; cc < 6; ++cc) {
      const int c = wv * 6 + cc;
      const u16* src;
      int dst, rowg;
      if (c < 8)       { src = Ah; dst = c * 512;               rowg = row0 + c * 16; }
      else if (c < 16) { src = Al; dst = 4096 + (c - 8) * 512;  rowg = row0 + (c - 8) * 16; }
      else if (c < 20) { src = Bh; dst = 8192 + (c - 16) * 512; rowg = col0 + (c - 16) * 16; }
      else             { src = Bl; dst = 10240 + (c - 20) * 512; rowg = col0 + (c - 20) * 16; }
      const u16* g = src + (size_t)(rowg + (ln >> 2)) * D_MODEL + kb + (ln & 3) * 8;
      __builtin_amdgcn_global_load_lds((const __attribute__((address_space(1))) void*)g,
                                       (__attribute__((address_space(3))) void*)(lds3 + dst),
                                       16, 0, 0);
    }
    __syncthreads();

    const int fr = ln & 15;
    const int ks = (ln >> 4) * 8;
    s16x8 a_h[4], a_l[4], b_h[2], b_l[2];
#pragma unroll
    for (int mi = 0; mi < 4; ++mi) {
      const int r = wr * 64 + mi * 16 + fr;
      a_h[mi] = *(const s16x8*)&smem[r * 32 + ks];
      a_l[mi] = *(const s16x8*)&smem[4096 + r * 32 + ks];
    }
#pragma unroll
    for (int ni = 0; ni < 2; ++ni) {
      const int r = wc * 32 + ni * 16 + fr;
      b_h[ni] = *(const s16x8*)&smem[8192 + r * 32 + ks];
      b_l[ni] = *(const s16x8*)&smem[10240 + r * 32 + ks];
    }
#pragma unroll
    for (int mi = 0; mi < 4; ++mi)
#pragma unroll
      for (int ni = 0; ni < 2; ++ni) {
        acc[mi][ni] = __builtin_amdgcn_mfma_f32_16x16x32_bf16(a_h[mi], b_h[ni], acc[mi][ni], 0, 0, 0);
        acc[mi][ni] = __builtin_amdgcn_mfma_f32_16x16x32_bf16(a_h[mi], b_l[ni], acc[mi][ni], 0, 0, 0);
        acc[mi][ni] = __builtin_amdgcn_mfma_f32_16x16x32_bf16(a_l[mi], b_h[ni], acc[mi][ni], 0, 0, 0);
      }
  }

  // epilogue: C/D layout col = lane&15, row = (lane>>4)*4 + reg
  const int fr = ln & 15, fq = ln >> 4;
  float bval[2];
  bval[0] = bias[col0 + wc * 32 + fr];
  bval[1] = bias[col0 + wc * 32 + 16 + fr];
#pragma unroll
  for (int mi = 0; mi < 4; ++mi)
#pragma unroll
    for (int ni = 0; ni < 2; ++ni)
#pragma unroll
      for (int j = 0; j < 4; ++j) {
        const int r  = row0 + wr * 64 + mi * 16 + fq * 4 + j;
        const int cg = col0 + wc * 32 + ni * 16 + fr;
        const float o = acc[mi][ni][j] + bval[ni];
        if (mode == 0) {
          Cf[(size_t)r * D_MODEL + cg] = o;
        } else {
          size_t idx;
          if (mode == 1) idx = (size_t)r * D_MODEL + cg;
          else           idx = ((size_t)(r >> 11) * D_MODEL + cg) * (size_t)MKTOK + (r & 2047);
          const u16 hb = f2bf(o);
          Ch[idx] = hb;
          Cl[idx] = f2bf(o - bf2f(hb));
        }
      }
}

// ---------------- MFMA banded attention ------------------------------------
// 1 wave per 32-query tile; 4 waves/block; 512 blocks (XCD-swizzled).
// QK^T split-bf16 (frags from global, L2-warm), softmax in registers,
// PV split-bf16 with P via per-wave LDS repack; V read pre-transposed.
__global__ __launch_bounds__(256)
void mfma_attn(const u16* __restrict__ Qh, const u16* __restrict__ Ql,
               const u16* __restrict__ Kh, const u16* __restrict__ Kl,
               const u16* __restrict__ Vth, const u16* __restrict__ Vtl,
               u16* __restrict__ AOh, u16* __restrict__ AOl) {
  __shared__ __align__(16) u16 Pbuf[4][2][32 * 40];   // 20.5 KB
  const int t = threadIdx.x, w = t >> 6, ln = t & 63;
  const int fr = ln & 15, fq = ln >> 4;
  int bb = blockIdx.x;
  bb = (bb & 7) * 64 + (bb >> 3);                     // XCD swizzle (512 = 8*64)
  const int g  = bb * 4 + w;                          // 0..2047 q-tiles
  const int qt = g & 63, h = (g >> 6) & 15, b = g >> 10;
  const int q0 = qt * 32;
  const int jlo = (q0 >= WHALF) ? q0 - WHALF : 0;
  const size_t tb = (size_t)b * NQTOK * D_MODEL;
  const int hc = h * HD;

  // Q fragments [mt][kt][hi/lo]
  s16x8 qf[2][2][2];
#pragma unroll
  for (int mt = 0; mt < 2; ++mt)
#pragma unroll
    for (int kt = 0; kt < 2; ++kt) {
      const size_t o = tb + (size_t)(q0 + mt * 16 + fr) * D_MODEL + hc + kt * 32 + fq * 8;
      qf[mt][kt][0] = *(const s16x8*)(Qh + o);
      qf[mt][kt][1] = *(const s16x8*)(Ql + o);
    }

  // logits: L[mt][nt] covers q-rows (fq*4+reg), key col (fr) of n-tile nt
  f32x4 L[2][10];
#pragma unroll
  for (int mt = 0; mt < 2; ++mt)
#pragma unroll
    for (int nt = 0; nt < 10; ++nt) L[mt][nt] = (f32x4){0.f, 0.f, 0.f, 0.f};
#pragma unroll
  for (int nt = 0; nt < 10; ++nt) {
    int jr = jlo + nt * 16 + fr;
    if (jr > MKTOK - 1) jr = MKTOK - 1;               // clamp (masked later)
#pragma unroll
    for (int kt = 0; kt < 2; ++kt) {
      const size_t o = tb + (size_t)jr * D_MODEL + hc + kt * 32 + fq * 8;
      const s16x8 kfh = *(const s16x8*)(Kh + o);
      const s16x8 kfl = *(const s16x8*)(Kl + o);
#pragma unroll
      for (int mt = 0; mt < 2; ++mt) {
        L[mt][nt] = __builtin_amdgcn_mfma_f32_16x16x32_bf16(qf[mt][kt][0], kfh, L[mt][nt], 0, 0, 0);
        L[mt][nt] = __builtin_amdgcn_mfma_f32_16x16x32_bf16(qf[mt][kt][0], kfl, L[mt][nt], 0, 0, 0);
        L[mt][nt] = __builtin_amdgcn_mfma_f32_16x16x32_bf16(qf[mt][kt][1], kfh, L[mt][nt], 0, 0, 0);
      }
    }
  }

  // masked softmax, fully in registers (cross-fr reduce = shfl_xor 1,2,4,8)
  float inv[2][4];
#pragma unroll
  for (int mt = 0; mt < 2; ++mt)
#pragma unroll
    for (int rg = 0; rg < 4; ++rg) {
      const int q = q0 + mt * 16 + fq * 4 + rg;
      float mx = -3.0e38f;
#pragma unroll
      for (int nt = 0; nt < 10; ++nt) {
        const int j = jlo + nt * 16 + fr;
        const int d = q - j;
        const bool ok = (d <= WHALF) && (d >= -WHALF) && (j < MKTOK);
        const float lv = ok ? L[mt][nt][rg] * 0.125f : -3.0e38f;
        L[mt][nt][rg] = lv;
        mx = fmaxf(mx, lv);
      }
      mx = fmaxf(mx, __shfl_xor(mx, 1));
      mx = fmaxf(mx, __shfl_xor(mx, 2));
      mx = fmaxf(mx, __shfl_xor(mx, 4));
      mx = fmaxf(mx, __shfl_xor(mx, 8));
      float sm = 0.f;
#pragma unroll
      for (int nt = 0; nt < 10; ++nt) {
        const float lv = L[mt][nt][rg];
        const float e = (lv > -1.0e38f) ? __expf(lv - mx) : 0.f;
        L[mt][nt][rg] = e;
        sm += e;
      }
      sm += __shfl_xor(sm, 1);
      sm += __shfl_xor(sm, 2);
      sm += __shfl_xor(sm, 4);
      sm += __shfl_xor(sm, 8);
      inv[mt][rg] = 1.f / sm;
    }

  // PV over 5 key-chunks of 32, P repacked through per-wave LDS
  f32x4 oacc[2][4];
#pragma unroll
  for (int mt = 0; mt < 2; ++mt)
#pragma unroll
    for (int nt = 0; nt < 4; ++nt) oacc[mt][nt] = (f32x4){0.f, 0.f, 0.f, 0.f};

  u16* ph = &Pbuf[w][0][0];
  u16* pl = &Pbuf[w][1][0];
#pragma unroll
  for (int c = 0; c < 5; ++c) {
    __syncthreads();                                  // prev chunk consumed
#pragma unroll
    for (int mt = 0; mt < 2; ++mt)
#pragma unroll
      for (int half = 0; half < 2; ++half) {
        const int nt = 2 * c + half;
#pragma unroll
        for (int rg = 0; rg < 4; ++rg) {
          const float v = L[mt][nt][rg] * inv[mt][rg];
          const u16 hb = f2bf(v);
          const int idx = (mt * 16 + fq * 4 + rg) * 40 + half * 16 + fr;
          ph[idx] = hb;
          pl[idx] = f2bf(v - bf2f(hb));
        }
      }
    __syncthreads();                                  // chunk visible
#pragma unroll
    for (int mt = 0; mt < 2; ++mt) {
      const s16x8 pfh = *(const s16x8*)&ph[(mt * 16 + fr) * 40 + fq * 8];
      const s16x8 pfl = *(const s16x8*)&pl[(mt * 16 + fr) * 40 + fq * 8];
      int tk = jlo + c * 32 + fq * 8;
      if (tk > MKTOK - 8) tk = MKTOK - 8;             // clamp; tk≡0 mod 8 so an
                                                      // OOB group is fully masked (P=0)
#pragma unroll
      for (int nt = 0; nt < 4; ++nt) {
        const size_t o = ((size_t)b * D_MODEL + hc + nt * 16 + fr) * (size_t)MKTOK + tk;
        const s16x8 vfh = *(const s16x8*)(Vth + o);
        const s16x8 vfl = *(const s16x8*)(Vtl + o);
        oacc[mt][nt] = __builtin_amdgcn_mfma_f32_16x16x32_bf16(pfh, vfh, oacc[mt][nt], 0, 0, 0);
        oacc[mt][nt] = __builtin_amdgcn_mfma_f32_16x16x32_bf16(pfh, vfl, oacc[mt][nt], 0, 0, 0);
        oacc[mt][nt] = __builtin_amdgcn_mfma_f32_16x16x32_bf16(pfl, vfh, oacc[mt][nt], 0, 0, 0);
      }
    }
  }

  // epilogue: AO split-bf16 for the final GEMM
#pragma unroll
  for (int mt = 0; mt < 2; ++mt)
#pragma unroll
    for (int nt = 0; nt < 4; ++nt)
#pragma unroll
      for (int j = 0; j < 4; ++j) {
        const int q = q0 + mt * 16 + fq * 4 + j;
        const int d = hc + nt * 16 + fr;
        const float o = oacc[mt][nt][j];
        const size_t idx = tb + (size_t)q * D_MODEL + d;
        const u16 hb = f2bf(o);
        AOh[idx] = hb;
        AOl[idx] = f2bf(o - bf2f(hb));
      }
}

// ---------------- fp32 fallback (round-3 verified) --------------------------
#define GBM 128
#define GBN 64
#define GBK 32
#define GSX 132
#define GSW 68

__global__ __launch_bounds__(256)
void proj_gemm(const float* __restrict__ X, const float* __restrict__ W,
               const float* __restrict__ bias, float* __restrict__ C) {
  __shared__ __align__(16) float Xs[GBK][GSX];
  __shared__ __align__(16) float Ws[GBK][GSW];
  const int t   = threadIdx.x;
  const int tx  = t & 15;
  const int ty  = t >> 4;
  const int row0 = blockIdx.x * GBM;
  const int col0 = blockIdx.y * GBN;
  float acc[8][4] = {};
  for (int kt = 0; kt < D_MODEL / GBK; ++kt) {
    const int kbase = kt * GBK;
    __syncthreads();
#pragma unroll
    for (int p = 0; p < 4; ++p) {
      const int idx = t + p * 256;
      const int r = idx >> 3, f = idx & 7;
      const float4 v = *(const float4*)(X + (size_t)(row0 + r) * D_MODEL + kbase + f * 4);
      Xs[f * 4 + 0][r] = v.x; Xs[f * 4 + 1][r] = v.y;
      Xs[f * 4 + 2][r] = v.z; Xs[f * 4 + 3][r] = v.w;
    }
#pragma unroll
    for (int p = 0; p < 2; ++p) {
      const int idx = t + p * 256;
      const int r = idx >> 3, f = idx & 7;
      const float4 v = *(const float4*)(W + (size_t)(col0 + r) * D_MODEL + kbase + f * 4);
      Ws[f * 4 + 0][r] = v.x; Ws[f * 4 + 1][r] = v.y;
      Ws[f * 4 + 2][r] = v.z; Ws[f * 4 + 3][r] = v.w;
    }
    __syncthreads();
#pragma unroll 4
    for (int kk = 0; kk < GBK; ++kk) {
      const float4 a0 = *(const float4*)&Xs[kk][ty * 8];
      const float4 a1 = *(const float4*)&Xs[kk][ty * 8 + 4];
      const float4 b  = *(const float4*)&Ws[kk][tx * 4];
      const float av[8] = {a0.x, a0.y, a0.z, a0.w, a1.x, a1.y, a1.z, a1.w};
      const float bv[4] = {b.x, b.y, b.z, b.w};
#pragma unroll
      for (int i = 0; i < 8; ++i)
#pragma unroll
        for (int j = 0; j < 4; ++j)
          acc[i][j] = fmaf(av[i], bv[j], acc[i][j]);
    }
  }
  const float4 b4 = *(const float4*)(bias + col0 + tx * 4);
#pragma unroll
  for (int i = 0; i < 8; ++i) {
    float4 o;
    o.x = acc[i][0] + b4.x; o.y = acc[i][1] + b4.y;
    o.z = acc[i][2] + b4.z; o.w = acc[i][3] + b4.w;
    *(float4*)(C + (size_t)(row0 + ty * 8 + i) * D_MODEL + col0 + tx * 4) = o;
  }
}

#define QB    32
#define CHUNK 80
#define KS    65
#define PS    161

__global__ __launch_bounds__(256)
void local_attn(const float* __restrict__ Q, const float* __restrict__ K,
                const float* __restrict__ V, float* __restrict__ AO) {
  __shared__ float Qs[QB][KS];
  __shared__ float KVs[CHUNK][KS];
  __shared__ float P[QB][PS];
  __shared__ float inv_s[QB];
  const int t = threadIdx.x;
  const int nqb = NQTOK / QB;
  const int bid = blockIdx.x;
  const int qb  = bid % nqb;
  const int h   = (bid / nqb) % N_HEADS;
  const int b   = bid / (nqb * N_HEADS);
  const int q0  = qb * QB;
  const int j_lo = max(0, q0 - WHALF);
  const int j_hi = min(MKTOK - 1, q0 + QB - 1 + WHALF);
  const int KB   = j_hi - j_lo + 1;
  const float scale = 0.125f;
  const size_t base = (size_t)b * NQTOK * D_MODEL + h * HD;
  const float* Qb = Q + base;
  const float* Kb = K + base;
  const float* Vb = V + base;
  for (int idx = t; idx < QB * 16; idx += 256) {
    const int r = idx >> 4, f = idx & 15;
    const float4 v = *(const float4*)(Qb + (size_t)(q0 + r) * D_MODEL + f * 4);
    Qs[r][f * 4 + 0] = v.x * scale; Qs[r][f * 4 + 1] = v.y * scale;
    Qs[r][f * 4 + 2] = v.z * scale; Qs[r][f * 4 + 3] = v.w * scale;
  }
  const int txk = t & 15;
  const int tyq = t >> 4;
  for (int c = 0; c < 2; ++c) {
    const int jc0 = c * CHUNK;
    const int cnt = min(CHUNK, KB - jc0);
    __syncthreads();
    for (int idx = t; idx < cnt * 16; idx += 256) {
      const int r = idx >> 4, f = idx & 15;
      const float4 v = *(const float4*)(Kb + (size_t)(j_lo + jc0 + r) * D_MODEL + f * 4);
      KVs[r][f * 4 + 0] = v.x; KVs[r][f * 4 + 1] = v.y;
      KVs[r][f * 4 + 2] = v.z; KVs[r][f * 4 + 3] = v.w;
    }
    __syncthreads();
    float acc[2][5] = {};
#pragma unroll 4
    for (int d = 0; d < HD; ++d) {
      const float q0v = Qs[2 * tyq + 0][d];
      const float q1v = Qs[2 * tyq + 1][d];
#pragma unroll
      for (int kc = 0; kc < 5; ++kc) {
        const float kv = KVs[txk * 5 + kc][d];
        acc[0][kc] = fmaf(q0v, kv, acc[0][kc]);
        acc[1][kc] = fmaf(q1v, kv, acc[1][kc]);
      }
    }
#pragma unroll
    for (int qc = 0; qc < 2; ++qc)
#pragma unroll
      for (int kc = 0; kc < 5; ++kc)
        P[2 * tyq + qc][jc0 + txk * 5 + kc] = acc[qc][kc];
  }
  __syncthreads();
  {
    const int q = t >> 3, s8 = t & 7;
    const int qi = q0 + q;
    float mx = -1e30f;
    for (int jj = s8; jj < KB; jj += 8) {
      int diff = qi - (j_lo + jj); if (diff < 0) diff = -diff;
      if (diff <= WHALF) mx = fmaxf(mx, P[q][jj]);
    }
    mx = fmaxf(mx, __shfl_xor(mx, 1));
    mx = fmaxf(mx, __shfl_xor(mx, 2));
    mx = fmaxf(mx, __shfl_xor(mx, 4));
    float sum = 0.f;
    for (int jj = s8; jj < KB; jj += 8) {
      int diff = qi - (j_lo + jj); if (diff < 0) diff = -diff;
      float e = 0.f;
      if (diff <= WHALF) { e = expf(P[q][jj] - mx); sum += e; }
      P[q][jj] = e;
    }
    sum += __shfl_xor(sum, 1);
    sum += __shfl_xor(sum, 2);
    sum += __shfl_xor(sum, 4);
    if (s8 == 0) inv_s[q] = 1.f / sum;
  }
  const int d  = t & 63;
  const int qg = t >> 6;
  float oacc[8] = {};
  for (int c = 0; c < 2; ++c) {
    const int jc0 = c * CHUNK;
    const int cnt = min(CHUNK, KB - jc0);
    __syncthreads();
    for (int idx = t; idx < cnt * 16; idx += 256) {
      const int r = idx >> 4, f = idx & 15;
      const float4 v = *(const float4*)(Vb + (size_t)(j_lo + jc0 + r) * D_MODEL + f * 4);
      KVs[r][f * 4 + 0] = v.x; KVs[r][f * 4 + 1] = v.y;
      KVs[r][f * 4 + 2] = v.z; KVs[r][f * 4 + 3] = v.w;
    }
    __syncthreads();
    for (int jj = 0; jj < cnt; ++jj) {
      const float v = KVs[jj][d];
#pragma unroll
      for (int i = 0; i < 8; ++i)
        oacc[i] = fmaf(P[qg * 8 + i][jc0 + jj], v, oacc[i]);
    }
  }
#pragma unroll
  for (int i = 0; i < 8; ++i) {
    const int q = qg * 8 + i;
    AO[base + (size_t)(q0 + q) * D_MODEL + d] = oacc[i] * inv_s[q];
  }
}

// ---------------------------------------------------------------------------
extern "C" void kernel_launch(void* const* d_in, const int* in_sizes, int n_in,
                              void* d_out, int out_size, void* d_ws, size_t ws_size,
                              hipStream_t stream) {
  const float* queries = (const float*)d_in[0];
  const float* keys    = (const float*)d_in[1];
  const float* values  = (const float*)d_in[2];
  const float* wq = (const float*)d_in[3];
  const float* bq = (const float*)d_in[4];
  const float* wk = (const float*)d_in[5];
  const float* bk = (const float*)d_in[6];
  const float* wv = (const float*)d_in[7];
  const float* bv = (const float*)d_in[8];
  const float* wo = (const float*)d_in[9];
  const float* bo = (const float*)d_in[10];
  float* out = (float*)d_out;

  const size_t mat  = MAT;
  const size_t wmat = WMAT;
  const size_t need = 117440512;   // (12*mat + 8*wmat) u16

  if (ws_size >= need) {
    u16* W = (u16*)d_ws;
    // layout: [xq h,l][xk h,l][xv h,l] [8 weight h/l] [q h,l][k h,l][vt h,l]
    u16* xqh = W;
    u16* xql = xqh + mat;
    u16* xkh = W + 2 * mat;
    u16* xkl = xkh + mat;
    u16* xvh = W + 4 * mat;
    u16* xvl = xvh + mat;
    u16* wgt = W + 6 * mat;
    u16* wqh = wgt;             u16* wql = wgt + wmat;
    u16* wkh = wgt + 2 * wmat;  u16* wkl = wgt + 3 * wmat;
    u16* wvh = wgt + 4 * wmat;  u16* wvl = wgt + 5 * wmat;
    u16* woh = wgt + 6 * wmat;  u16* wol = wgt + 7 * wmat;
    u16* outs = wgt + 8 * wmat;
    u16* qh  = outs;            u16* ql  = outs + mat;
    u16* kh  = outs + 2 * mat;  u16* kl  = outs + 3 * mat;
    u16* vth = outs + 4 * mat;  u16* vtl = outs + 5 * mat;
    u16* aoh = xqh;             u16* aol = xql;   // alias: dead after Q-GEMM

    cvt_all<<<dim3(8192), 256, 0, stream>>>(queries, keys, values, wq, wk, wv, wo, W);

    const dim3 gm(BATCH * NQTOK / TBM, D_MODEL / TBN);   // 32 x 16
    mfma_gemm<<<gm, 256, 0, stream>>>(xqh, xql, wqh, wql, bq, nullptr, qh, ql, 1);
    mfma_gemm<<<gm, 256, 0, stream>>>(xkh, xkl, wkh, wkl, bk, nullptr, kh, kl, 1);
    mfma_gemm<<<gm, 256, 0, stream>>>(xvh, xvl, wvh, wvl, bv, nullptr, vth, vtl, 2);

    mfma_attn<<<dim3(512), 256, 0, stream>>>(qh, ql, kh, kl, vth, vtl, aoh, aol);

    mfma_gemm<<<gm, 256, 0, stream>>>(aoh, aol, woh, wol, bo, out, nullptr, nullptr, 0);
  } else {
    float* Qws = (float*)d_ws;
    float* Kws = Qws + mat;
    float* Vws = Kws + mat;
    float* AOws = Qws;
    const dim3 gg(BATCH * NQTOK / GBM, D_MODEL / GBN);
    proj_gemm<<<gg, 256, 0, stream>>>(queries, wq, bq, Qws);
    proj_gemm<<<gg, 256, 0, stream>>>(keys,    wk, bk, Kws);
    proj_gemm<<<gg, 256, 0, stream>>>(values,  wv, bv, Vws);
    local_attn<<<dim3(BATCH * N_HEADS * (NQTOK / QB)), 256, 0, stream>>>(Qws, Kws, Vws, AOws);
    proj_gemm<<<gg, 256, 0, stream>>>(AOws, wo, bo, out);
  }
}

// Round 11
// 297.711 us; speedup vs baseline: 2.6110x; 1.0128x over previous
//
#include <hip/hip_runtime.h>
#include <math.h>

// ---------------------------------------------------------------------------
// LocalAttention. Round 11: fused QKV projection GEMM (one dispatch, 128x128
// tile, 3 blocks/CU) on top of the round-10 verified MFMA pipeline.
// Projections + attention all split-bf16 MFMA (fp32-grade, absmax 4.9e-4).
// ---------------------------------------------------------------------------

#define D_MODEL 1024
#define N_HEADS 16
#define HD      64
#define WHALF   64
#define BATCH   2
#define NQTOK   2048
#define MKTOK   2048

typedef float f32x4 __attribute__((ext_vector_type(4)));
typedef short s16x8 __attribute__((ext_vector_type(8)));
typedef unsigned short u16;

static __device__ __forceinline__ u16 f2bf(float x) {
  unsigned u = __float_as_uint(x);
  unsigned r = (u + 0x7fffu + ((u >> 16) & 1u)) >> 16;   // RTNE
  return (u16)r;
}
static __device__ __forceinline__ float bf2f(u16 h) {
  return __uint_as_float(((unsigned)h) << 16);
}

// ---------------- fused fp32 -> (bf16 hi, bf16 lo) for all 7 inputs --------
#define MAT  4194304u
#define WMAT 1048576u

__global__ __launch_bounds__(256)
void cvt_all(const float* __restrict__ q, const float* __restrict__ k,
             const float* __restrict__ v, const float* __restrict__ wq,
             const float* __restrict__ wk, const float* __restrict__ wv,
             const float* __restrict__ wo, u16* __restrict__ W) {
  const unsigned g = blockIdx.x * 256 + threadIdx.x;  // 0 .. 2097151
  const float* src;
  size_t dbase; unsigned off;
  if (g < 524288u)        { src = q;  dbase = 0;                  off = g; }
  else if (g < 1048576u)  { src = k;  dbase = 2u * MAT;           off = g - 524288u; }
  else if (g < 1572864u)  { src = v;  dbase = 4u * MAT;           off = g - 1048576u; }
  else if (g < 1703936u)  { src = wq; dbase = 6u * (size_t)MAT;               off = g - 1572864u; }
  else if (g < 1835008u)  { src = wk; dbase = 6u * (size_t)MAT + 2u * WMAT;   off = g - 1703936u; }
  else if (g < 1966080u)  { src = wv; dbase = 6u * (size_t)MAT + 4u * WMAT;   off = g - 1835008u; }
  else                    { src = wo; dbase = 6u * (size_t)MAT + 6u * WMAT;   off = g - 1966080u; }
  const size_t stride = (dbase < 6u * (size_t)MAT) ? MAT : WMAT;   // hi->lo distance
  u16* dh = W + dbase;
  u16* dl = dh + stride;
  const size_t e = (size_t)off * 8;
  const float4 v0 = *(const float4*)(src + e);
  const float4 v1 = *(const float4*)(src + e + 4);
  const float xs[8] = {v0.x, v0.y, v0.z, v0.w, v1.x, v1.y, v1.z, v1.w};
  u16 hs[8], ls[8];
#pragma unroll
  for (int i = 0; i < 8; ++i) {
    hs[i] = f2bf(xs[i]);
    ls[i] = f2bf(xs[i] - bf2f(hs[i]));
  }
  uint4 hv, lv;
  hv.x = hs[0] | ((unsigned)hs[1] << 16); hv.y = hs[2] | ((unsigned)hs[3] << 16);
  hv.z = hs[4] | ((unsigned)hs[5] << 16); hv.w = hs[6] | ((unsigned)hs[7] << 16);
  lv.x = ls[0] | ((unsigned)ls[1] << 16); lv.y = ls[2] | ((unsigned)ls[3] << 16);
  lv.z = ls[4] | ((unsigned)ls[5] << 16); lv.w = ls[6] | ((unsigned)ls[7] << 16);
  *(uint4*)(dh + e) = hv;
  *(uint4*)(dl + e) = lv;
}

// ---------------- fused QKV split-bf16 MFMA GEMM ----------------------------
// One dispatch for all three projections. grid 768 blocks (bijective XCD
// swizzle), 128x128 tile, BK=32, 4 waves (2x2), wave tile 64x64.
// z=0 (Q), z=1 (K): hi/lo out at [tok][d]. z=2 (V): transposed [b][d][tok].
__global__ __launch_bounds__(256)
void mfma_gemm_qkv(u16* __restrict__ W, const float* __restrict__ bq,
                   const float* __restrict__ bk, const float* __restrict__ bv) {
  __shared__ u16 smem[16384];           // 32 KB: Ah@0 Al@4096 Bh@8192 Bl@12288
  const int t  = threadIdx.x;
  const int wv = t >> 6;
  const int ln = t & 63;
  const int wr = wv >> 1, wc = wv & 1;

  int lin = blockIdx.x;                 // 0..767, 768 % 8 == 0 -> bijective
  lin = (lin & 7) * 96 + (lin >> 3);    // XCD-chunked swizzle
  const int bz   = lin >> 8;            // 0..2  (which projection)
  const int rem  = lin & 255;
  const int row0 = (rem & 31) * 128;    // 32 row-tiles
  const int col0 = (rem >> 5) * 128;    // 8 col-tiles

  const u16* Ah = W + (size_t)2 * bz * MAT;
  const u16* Al = Ah + MAT;
  const u16* Bh = W + 6u * (size_t)MAT + (size_t)2 * bz * WMAT;
  const u16* Bl = Bh + WMAT;
  u16* Ch = W + 6u * (size_t)MAT + 8u * (size_t)WMAT + (size_t)2 * bz * MAT;
  u16* Cl = Ch + MAT;
  const float* bias = (bz == 0) ? bq : ((bz == 1) ? bk : bv);

  f32x4 acc[4][4];
#pragma unroll
  for (int mi = 0; mi < 4; ++mi)
#pragma unroll
    for (int ni = 0; ni < 4; ++ni)
      acc[mi][ni] = (f32x4){0.f, 0.f, 0.f, 0.f};

  auto lds3 = (__attribute__((address_space(3))) u16*)smem;

  for (int kt = 0; kt < D_MODEL / 32; ++kt) {
    const int kb = kt * 32;
    if (kt) __syncthreads();
    // stage 32 x 1KB chunks (A 16KB hi+lo, B 16KB hi+lo), 8 per wave
#pragma unroll
    for (int cc = 0; cc < 8; ++cc) {
      const int c = wv * 8 + cc;
      const u16* src;
      int dst, rowg;
      if (c < 8)       { src = Ah; dst = c * 512;                rowg = row0 + c * 16; }
      else if (c < 16) { src = Al; dst = 4096 + (c - 8) * 512;   rowg = row0 + (c - 8) * 16; }
      else if (c < 24) { src = Bh; dst = 8192 + (c - 16) * 512;  rowg = col0 + (c - 16) * 16; }
      else             { src = Bl; dst = 12288 + (c - 24) * 512; rowg = col0 + (c - 24) * 16; }
      const u16* g = src + (size_t)(rowg + (ln >> 2)) * D_MODEL + kb + (ln & 3) * 8;
      __builtin_amdgcn_global_load_lds((const __attribute__((address_space(1))) void*)g,
                                       (__attribute__((address_space(3))) void*)(lds3 + dst),
                                       16, 0, 0);
    }
    __syncthreads();

    const int fr = ln & 15;
    const int ks = (ln >> 4) * 8;
    s16x8 a_h[4], a_l[4], b_h[4], b_l[4];
#pragma unroll
    for (int mi = 0; mi < 4; ++mi) {
      const int r = wr * 64 + mi * 16 + fr;
      a_h[mi] = *(const s16x8*)&smem[r * 32 + ks];
      a_l[mi] = *(const s16x8*)&smem[4096 + r * 32 + ks];
    }
#pragma unroll
    for (int ni = 0; ni < 4; ++ni) {
      const int r = wc * 64 + ni * 16 + fr;
      b_h[ni] = *(const s16x8*)&smem[8192 + r * 32 + ks];
      b_l[ni] = *(const s16x8*)&smem[12288 + r * 32 + ks];
    }
#pragma unroll
    for (int mi = 0; mi < 4; ++mi)
#pragma unroll
      for (int ni = 0; ni < 4; ++ni) {
        acc[mi][ni] = __builtin_amdgcn_mfma_f32_16x16x32_bf16(a_h[mi], b_h[ni], acc[mi][ni], 0, 0, 0);
        acc[mi][ni] = __builtin_amdgcn_mfma_f32_16x16x32_bf16(a_h[mi], b_l[ni], acc[mi][ni], 0, 0, 0);
        acc[mi][ni] = __builtin_amdgcn_mfma_f32_16x16x32_bf16(a_l[mi], b_h[ni], acc[mi][ni], 0, 0, 0);
      }
  }

  // epilogue: C/D layout col = lane&15, row = (lane>>4)*4 + reg
  const int fr = ln & 15, fq = ln >> 4;
  float bval[4];
#pragma unroll
  for (int ni = 0; ni < 4; ++ni)
    bval[ni] = bias[col0 + wc * 64 + ni * 16 + fr];
#pragma unroll
  for (int mi = 0; mi < 4; ++mi)
#pragma unroll
    for (int ni = 0; ni < 4; ++ni)
#pragma unroll
      for (int j = 0; j < 4; ++j) {
        const int r  = row0 + wr * 64 + mi * 16 + fq * 4 + j;
        const int cg = col0 + wc * 64 + ni * 16 + fr;
        const float o = acc[mi][ni][j] + bval[ni];
        size_t idx;
        if (bz != 2) idx = (size_t)r * D_MODEL + cg;                              // [tok][d]
        else         idx = ((size_t)(r >> 11) * D_MODEL + cg) * (size_t)MKTOK + (r & 2047); // Vt[b][d][tok]
        const u16 hb = f2bf(o);
        Ch[idx] = hb;
        Cl[idx] = f2bf(o - bf2f(hb));
      }
}

// ---------------- split-bf16 MFMA GEMM (final projection, mode-0 fp32 out) --
#define TBM 128
#define TBN 64
#define TBK 32

__global__ __launch_bounds__(256)
void mfma_gemm(const u16* __restrict__ Ah, const u16* __restrict__ Al,
               const u16* __restrict__ Bh, const u16* __restrict__ Bl,
               const float* __restrict__ bias, float* __restrict__ Cf) {
  __shared__ u16 smem[12288];           // 24 KB
  const int t  = threadIdx.x;
  const int wv = t >> 6;
  const int ln = t & 63;
  const int row0 = blockIdx.x * TBM;
  const int col0 = blockIdx.y * TBN;
  const int wr = wv >> 1, wc = wv & 1;

  f32x4 acc[4][2];
#pragma unroll
  for (int mi = 0; mi < 4; ++mi)
#pragma unroll
    for (int ni = 0; ni < 2; ++ni)
      acc[mi][ni] = (f32x4){0.f, 0.f, 0.f, 0.f};

  auto lds3 = (__attribute__((address_space(3))) u16*)smem;

  for (int kt = 0; kt < D_MODEL / TBK; ++kt) {
    const int kb = kt * TBK;
    if (kt) __syncthreads();
#pragma unroll
    for (int cc = 0; cc < 6; ++cc) {
      const int c = wv * 6 + cc;
      const u16* src;
      int dst, rowg;
      if (c < 8)       { src = Ah; dst = c * 512;               rowg = row0 + c * 16; }
      else if (c < 16) { src = Al; dst = 4096 + (c - 8) * 512;  rowg = row0 + (c - 8) * 16; }
      else if (c < 20) { src = Bh; dst = 8192 + (c - 16) * 512; rowg = col0 + (c - 16) * 16; }
      else             { src = Bl; dst = 10240 + (c - 20) * 512; rowg = col0 + (c - 20) * 16; }
      const u16* g = src + (size_t)(rowg + (ln >> 2)) * D_MODEL + kb + (ln & 3) * 8;
      __builtin_amdgcn_global_load_lds((const __attribute__((address_space(1))) void*)g,
                                       (__attribute__((address_space(3))) void*)(lds3 + dst),
                                       16, 0, 0);
    }
    __syncthreads();

    const int fr = ln & 15;
    const int ks = (ln >> 4) * 8;
    s16x8 a_h[4], a_l[4], b_h[2], b_l[2];
#pragma unroll
    for (int mi = 0; mi < 4; ++mi) {
      const int r = wr * 64 + mi * 16 + fr;
      a_h[mi] = *(const s16x8*)&smem[r * 32 + ks];
      a_l[mi] = *(const s16x8*)&smem[4096 + r * 32 + ks];
    }
#pragma unroll
    for (int ni = 0; ni < 2; ++ni) {
      const int r = wc * 32 + ni * 16 + fr;
      b_h[ni] = *(const s16x8*)&smem[8192 + r * 32 + ks];
      b_l[ni] = *(const s16x8*)&smem[10240 + r * 32 + ks];
    }
#pragma unroll
    for (int mi = 0; mi < 4; ++mi)
#pragma unroll
      for (int ni = 0; ni < 2; ++ni) {
        acc[mi][ni] = __builtin_amdgcn_mfma_f32_16x16x32_bf16(a_h[mi], b_h[ni], acc[mi][ni], 0, 0, 0);
        acc[mi][ni] = __builtin_amdgcn_mfma_f32_16x16x32_bf16(a_h[mi], b_l[ni], acc[mi][ni], 0, 0, 0);
        acc[mi][ni] = __builtin_amdgcn_mfma_f32_16x16x32_bf16(a_l[mi], b_h[ni], acc[mi][ni], 0, 0, 0);
      }
  }

  const int fr = ln & 15, fq = ln >> 4;
  float bval[2];
  bval[0] = bias[col0 + wc * 32 + fr];
  bval[1] = bias[col0 + wc * 32 + 16 + fr];
#pragma unroll
  for (int mi = 0; mi < 4; ++mi)
#pragma unroll
    for (int ni = 0; ni < 2; ++ni)
#pragma unroll
      for (int j = 0; j < 4; ++j) {
        const int r  = row0 + wr * 64 + mi * 16 + fq * 4 + j;
        const int cg = col0 + wc * 32 + ni * 16 + fr;
        Cf[(size_t)r * D_MODEL + cg] = acc[mi][ni][j] + bval[ni];
      }
}

// ---------------- MFMA banded attention (round-10 verified, unchanged) ------
__global__ __launch_bounds__(256)
void mfma_attn(const u16* __restrict__ Qh, const u16* __restrict__ Ql,
               const u16* __restrict__ Kh, const u16* __restrict__ Kl,
               const u16* __restrict__ Vth, const u16* __restrict__ Vtl,
               u16* __restrict__ AOh, u16* __restrict__ AOl) {
  __shared__ __align__(16) u16 Pbuf[4][2][32 * 40];   // 20.5 KB
  const int t = threadIdx.x, w = t >> 6, ln = t & 63;
  const int fr = ln & 15, fq = ln >> 4;
  int bb = blockIdx.x;
  bb = (bb & 7) * 64 + (bb >> 3);                     // XCD swizzle (512 = 8*64)
  const int g  = bb * 4 + w;                          // 0..2047 q-tiles
  const int qt = g & 63, h = (g >> 6) & 15, b = g >> 10;
  const int q0 = qt * 32;
  const int jlo = (q0 >= WHALF) ? q0 - WHALF : 0;
  const size_t tb = (size_t)b * NQTOK * D_MODEL;
  const int hc = h * HD;

  s16x8 qf[2][2][2];
#pragma unroll
  for (int mt = 0; mt < 2; ++mt)
#pragma unroll
    for (int kt = 0; kt < 2; ++kt) {
      const size_t o = tb + (size_t)(q0 + mt * 16 + fr) * D_MODEL + hc + kt * 32 + fq * 8;
      qf[mt][kt][0] = *(const s16x8*)(Qh + o);
      qf[mt][kt][1] = *(const s16x8*)(Ql + o);
    }

  f32x4 L[2][10];
#pragma unroll
  for (int mt = 0; mt < 2; ++mt)
#pragma unroll
    for (int nt = 0; nt < 10; ++nt) L[mt][nt] = (f32x4){0.f, 0.f, 0.f, 0.f};
#pragma unroll
  for (int nt = 0; nt < 10; ++nt) {
    int jr = jlo + nt * 16 + fr;
    if (jr > MKTOK - 1) jr = MKTOK - 1;               // clamp (masked later)
#pragma unroll
    for (int kt = 0; kt < 2; ++kt) {
      const size_t o = tb + (size_t)jr * D_MODEL + hc + kt * 32 + fq * 8;
      const s16x8 kfh = *(const s16x8*)(Kh + o);
      const s16x8 kfl = *(const s16x8*)(Kl + o);
#pragma unroll
      for (int mt = 0; mt < 2; ++mt) {
        L[mt][nt] = __builtin_amdgcn_mfma_f32_16x16x32_bf16(qf[mt][kt][0], kfh, L[mt][nt], 0, 0, 0);
        L[mt][nt] = __builtin_amdgcn_mfma_f32_16x16x32_bf16(qf[mt][kt][0], kfl, L[mt][nt], 0, 0, 0);
        L[mt][nt] = __builtin_amdgcn_mfma_f32_16x16x32_bf16(qf[mt][kt][1], kfh, L[mt][nt], 0, 0, 0);
      }
    }
  }

  float inv[2][4];
#pragma unroll
  for (int mt = 0; mt < 2; ++mt)
#pragma unroll
    for (int rg = 0; rg < 4; ++rg) {
      const int q = q0 + mt * 16 + fq * 4 + rg;
      float mx = -3.0e38f;
#pragma unroll
      for (int nt = 0; nt < 10; ++nt) {
        const int j = jlo + nt * 16 + fr;
        const int d = q - j;
        const bool ok = (d <= WHALF) && (d >= -WHALF) && (j < MKTOK);
        const float lv = ok ? L[mt][nt][rg] * 0.125f : -3.0e38f;
        L[mt][nt][rg] = lv;
        mx = fmaxf(mx, lv);
      }
      mx = fmaxf(mx, __shfl_xor(mx, 1));
      mx = fmaxf(mx, __shfl_xor(mx, 2));
      mx = fmaxf(mx, __shfl_xor(mx, 4));
      mx = fmaxf(mx, __shfl_xor(mx, 8));
      float sm = 0.f;
#pragma unroll
      for (int nt = 0; nt < 10; ++nt) {
        const float lv = L[mt][nt][rg];
        const float e = (lv > -1.0e38f) ? __expf(lv - mx) : 0.f;
        L[mt][nt][rg] = e;
        sm += e;
      }
      sm += __shfl_xor(sm, 1);
      sm += __shfl_xor(sm, 2);
      sm += __shfl_xor(sm, 4);
      sm += __shfl_xor(sm, 8);
      inv[mt][rg] = 1.f / sm;
    }

  f32x4 oacc[2][4];
#pragma unroll
  for (int mt = 0; mt < 2; ++mt)
#pragma unroll
    for (int nt = 0; nt < 4; ++nt) oacc[mt][nt] = (f32x4){0.f, 0.f, 0.f, 0.f};

  u16* ph = &Pbuf[w][0][0];
  u16* pl = &Pbuf[w][1][0];
#pragma unroll
  for (int c = 0; c < 5; ++c) {
    __syncthreads();
#pragma unroll
    for (int mt = 0; mt < 2; ++mt)
#pragma unroll
      for (int half = 0; half < 2; ++half) {
        const int nt = 2 * c + half;
#pragma unroll
        for (int rg = 0; rg < 4; ++rg) {
          const float v = L[mt][nt][rg] * inv[mt][rg];
          const u16 hb = f2bf(v);
          const int idx = (mt * 16 + fq * 4 + rg) * 40 + half * 16 + fr;
          ph[idx] = hb;
          pl[idx] = f2bf(v - bf2f(hb));
        }
      }
    __syncthreads();
#pragma unroll
    for (int mt = 0; mt < 2; ++mt) {
      const s16x8 pfh = *(const s16x8*)&ph[(mt * 16 + fr) * 40 + fq * 8];
      const s16x8 pfl = *(const s16x8*)&pl[(mt * 16 + fr) * 40 + fq * 8];
      int tk = jlo + c * 32 + fq * 8;
      if (tk > MKTOK - 8) tk = MKTOK - 8;             // clamp; tk≡0 mod 8 -> OOB group fully masked
#pragma unroll
      for (int nt = 0; nt < 4; ++nt) {
        const size_t o = ((size_t)b * D_MODEL + hc + nt * 16 + fr) * (size_t)MKTOK + tk;
        const s16x8 vfh = *(const s16x8*)(Vth + o);
        const s16x8 vfl = *(const s16x8*)(Vtl + o);
        oacc[mt][nt] = __builtin_amdgcn_mfma_f32_16x16x32_bf16(pfh, vfh, oacc[mt][nt], 0, 0, 0);
        oacc[mt][nt] = __builtin_amdgcn_mfma_f32_16x16x32_bf16(pfh, vfl, oacc[mt][nt], 0, 0, 0);
        oacc[mt][nt] = __builtin_amdgcn_mfma_f32_16x16x32_bf16(pfl, vfh, oacc[mt][nt], 0, 0, 0);
      }
    }
  }

#pragma unroll
  for (int mt = 0; mt < 2; ++mt)
#pragma unroll
    for (int nt = 0; nt < 4; ++nt)
#pragma unroll
      for (int j = 0; j < 4; ++j) {
        const int q = q0 + mt * 16 + fq * 4 + j;
        const int d = hc + nt * 16 + fr;
        const float o = oacc[mt][nt][j];
        const size_t idx = tb + (size_t)q * D_MODEL + d;
        const u16 hb = f2bf(o);
        AOh[idx] = hb;
        AOl[idx] = f2bf(o - bf2f(hb));
      }
}

// ---------------- fp32 fallback (round-3 verified) --------------------------
#define GBM 128
#define GBN 64
#define GBK 32
#define GSX 132
#define GSW 68

__global__ __launch_bounds__(256)
void proj_gemm(const float* __restrict__ X, const float* __restrict__ W,
               const float* __restrict__ bias, float* __restrict__ C) {
  __shared__ __align__(16) float Xs[GBK][GSX];
  __shared__ __align__(16) float Ws[GBK][GSW];
  const int t   = threadIdx.x;
  const int tx  = t & 15;
  const int ty  = t >> 4;
  const int row0 = blockIdx.x * GBM;
  const int col0 = blockIdx.y * GBN;
  float acc[8][4] = {};
  for (int kt = 0; kt < D_MODEL / GBK; ++kt) {
    const int kbase = kt * GBK;
    __syncthreads();
#pragma unroll
    for (int p = 0; p < 4; ++p) {
      const int idx = t + p * 256;
      const int r = idx >> 3, f = idx & 7;
      const float4 v = *(const float4*)(X + (size_t)(row0 + r) * D_MODEL + kbase + f * 4);
      Xs[f * 4 + 0][r] = v.x; Xs[f * 4 + 1][r] = v.y;
      Xs[f * 4 + 2][r] = v.z; Xs[f * 4 + 3][r] = v.w;
    }
#pragma unroll
    for (int p = 0; p < 2; ++p) {
      const int idx = t + p * 256;
      const int r = idx >> 3, f = idx & 7;
      const float4 v = *(const float4*)(W + (size_t)(col0 + r) * D_MODEL + kbase + f * 4);
      Ws[f * 4 + 0][r] = v.x; Ws[f * 4 + 1][r] = v.y;
      Ws[f * 4 + 2][r] = v.z; Ws[f * 4 + 3][r] = v.w;
    }
    __syncthreads();
#pragma unroll 4
    for (int kk = 0; kk < GBK; ++kk) {
      const float4 a0 = *(const float4*)&Xs[kk][ty * 8];
      const float4 a1 = *(const float4*)&Xs[kk][ty * 8 + 4];
      const float4 b  = *(const float4*)&Ws[kk][tx * 4];
      const float av[8] = {a0.x, a0.y, a0.z, a0.w, a1.x, a1.y, a1.z, a1.w};
      const float bv[4] = {b.x, b.y, b.z, b.w};
#pragma unroll
      for (int i = 0; i < 8; ++i)
#pragma unroll
        for (int j = 0; j < 4; ++j)
          acc[i][j] = fmaf(av[i], bv[j], acc[i][j]);
    }
  }
  const float4 b4 = *(const float4*)(bias + col0 + tx * 4);
#pragma unroll
  for (int i = 0; i < 8; ++i) {
    float4 o;
    o.x = acc[i][0] + b4.x; o.y = acc[i][1] + b4.y;
    o.z = acc[i][2] + b4.z; o.w = acc[i][3] + b4.w;
    *(float4*)(C + (size_t)(row0 + ty * 8 + i) * D_MODEL + col0 + tx * 4) = o;
  }
}

#define QB    32
#define CHUNK 80
#define KS    65
#define PS    161

__global__ __launch_bounds__(256)
void local_attn(const float* __restrict__ Q, const float* __restrict__ K,
                const float* __restrict__ V, float* __restrict__ AO) {
  __shared__ float Qs[QB][KS];
  __shared__ float KVs[CHUNK][KS];
  __shared__ float P[QB][PS];
  __shared__ float inv_s[QB];
  const int t = threadIdx.x;
  const int nqb = NQTOK / QB;
  const int bid = blockIdx.x;
  const int qb  = bid % nqb;
  const int h   = (bid / nqb) % N_HEADS;
  const int b   = bid / (nqb * N_HEADS);
  const int q0  = qb * QB;
  const int j_lo = max(0, q0 - WHALF);
  const int j_hi = min(MKTOK - 1, q0 + QB - 1 + WHALF);
  const int KB   = j_hi - j_lo + 1;
  const float scale = 0.125f;
  const size_t base = (size_t)b * NQTOK * D_MODEL + h * HD;
  const float* Qb = Q + base;
  const float* Kb = K + base;
  const float* Vb = V + base;
  for (int idx = t; idx < QB * 16; idx += 256) {
    const int r = idx >> 4, f = idx & 15;
    const float4 v = *(const float4*)(Qb + (size_t)(q0 + r) * D_MODEL + f * 4);
    Qs[r][f * 4 + 0] = v.x * scale; Qs[r][f * 4 + 1] = v.y * scale;
    Qs[r][f * 4 + 2] = v.z * scale; Qs[r][f * 4 + 3] = v.w * scale;
  }
  const int txk = t & 15;
  const int tyq = t >> 4;
  for (int c = 0; c < 2; ++c) {
    const int jc0 = c * CHUNK;
    const int cnt = min(CHUNK, KB - jc0);
    __syncthreads();
    for (int idx = t; idx < cnt * 16; idx += 256) {
      const int r = idx >> 4, f = idx & 15;
      const float4 v = *(const float4*)(Kb + (size_t)(j_lo + jc0 + r) * D_MODEL + f * 4);
      KVs[r][f * 4 + 0] = v.x; KVs[r][f * 4 + 1] = v.y;
      KVs[r][f * 4 + 2] = v.z; KVs[r][f * 4 + 3] = v.w;
    }
    __syncthreads();
    float acc[2][5] = {};
#pragma unroll 4
    for (int d = 0; d < HD; ++d) {
      const float q0v = Qs[2 * tyq + 0][d];
      const float q1v = Qs[2 * tyq + 1][d];
#pragma unroll
      for (int kc = 0; kc < 5; ++kc) {
        const float kv = KVs[txk * 5 + kc][d];
        acc[0][kc] = fmaf(q0v, kv, acc[0][kc]);
        acc[1][kc] = fmaf(q1v, kv, acc[1][kc]);
      }
    }
#pragma unroll
    for (int qc = 0; qc < 2; ++qc)
#pragma unroll
      for (int kc = 0; kc < 5; ++kc)
        P[2 * tyq + qc][jc0 + txk * 5 + kc] = acc[qc][kc];
  }
  __syncthreads();
  {
    const int q = t >> 3, s8 = t & 7;
    const int qi = q0 + q;
    float mx = -1e30f;
    for (int jj = s8; jj < KB; jj += 8) {
      int diff = qi - (j_lo + jj); if (diff < 0) diff = -diff;
      if (diff <= WHALF) mx = fmaxf(mx, P[q][jj]);
    }
    mx = fmaxf(mx, __shfl_xor(mx, 1));
    mx = fmaxf(mx, __shfl_xor(mx, 2));
    mx = fmaxf(mx, __shfl_xor(mx, 4));
    float sum = 0.f;
    for (int jj = s8; jj < KB; jj += 8) {
      int diff = qi - (j_lo + jj); if (diff < 0) diff = -diff;
      float e = 0.f;
      if (diff <= WHALF) { e = expf(P[q][jj] - mx); sum += e; }
      P[q][jj] = e;
    }
    sum += __shfl_xor(sum, 1);
    sum += __shfl_xor(sum, 2);
    sum += __shfl_xor(sum, 4);
    if (s8 == 0) inv_s[q] = 1.f / sum;
  }
  const int d  = t & 63;
  const int qg = t >> 6;
  float oacc[8] = {};
  for (int c = 0; c < 2; ++c) {
    const int jc0 = c * CHUNK;
    const int cnt = min(CHUNK, KB - jc0);
    __syncthreads();
    for (int idx = t; idx < cnt * 16; idx += 256) {
      const int r = idx >> 4, f = idx & 15;
      const float4 v = *(const float4*)(Vb + (size_t)(j_lo + jc0 + r) * D_MODEL + f * 4);
      KVs[r][f * 4 + 0] = v.x; KVs[r][f * 4 + 1] = v.y;
      KVs[r][f * 4 + 2] = v.z; KVs[r][f * 4 + 3] = v.w;
    }
    __syncthreads();
    for (int jj = 0; jj < cnt; ++jj) {
      const float v = KVs[jj][d];
#pragma unroll
      for (int i = 0; i < 8; ++i)
        oacc[i] = fmaf(P[qg * 8 + i][jc0 + jj], v, oacc[i]);
    }
  }
#pragma unroll
  for (int i = 0; i < 8; ++i) {
    const int q = qg * 8 + i;
    AO[base + (size_t)(q0 + q) * D_MODEL + d] = oacc[i] * inv_s[q];
  }
}

// ---------------------------------------------------------------------------
extern "C" void kernel_launch(void* const* d_in, const int* in_sizes, int n_in,
                              void* d_out, int out_size, void* d_ws, size_t ws_size,
                              hipStream_t stream) {
  const float* queries = (const float*)d_in[0];
  const float* keys    = (const float*)d_in[1];
  const float* values  = (const float*)d_in[2];
  const float* wq = (const float*)d_in[3];
  const float* bq = (const float*)d_in[4];
  const float* wk = (const float*)d_in[5];
  const float* bk = (const float*)d_in[6];
  const float* wv = (const float*)d_in[7];
  const float* bv = (const float*)d_in[8];
  const float* wo = (const float*)d_in[9];
  const float* bo = (const float*)d_in[10];
  float* out = (float*)d_out;

  const size_t mat  = MAT;
  const size_t wmat = WMAT;
  const size_t need = 117440512;   // (12*mat + 8*wmat) u16

  if (ws_size >= need) {
    u16* W = (u16*)d_ws;
    // layout: [xq h,l][xk h,l][xv h,l] [8 weight h/l] [q h,l][k h,l][vt h,l]
    u16* wgt = W + 6 * mat;
    u16* woh = wgt + 6 * wmat;  u16* wol = wgt + 7 * wmat;
    u16* outs = wgt + 8 * wmat;
    u16* qh  = outs;            u16* ql  = outs + mat;
    u16* kh  = outs + 2 * mat;  u16* kl  = outs + 3 * mat;
    u16* vth = outs + 4 * mat;  u16* vtl = outs + 5 * mat;
    u16* aoh = W;               u16* aol = W + mat;   // alias xq conv (dead after QKV GEMM)

    cvt_all<<<dim3(8192), 256, 0, stream>>>(queries, keys, values, wq, wk, wv, wo, W);

    mfma_gemm_qkv<<<dim3(768), 256, 0, stream>>>(W, bq, bk, bv);

    mfma_attn<<<dim3(512), 256, 0, stream>>>(qh, ql, kh, kl, vth, vtl, aoh, aol);

    mfma_gemm<<<dim3(BATCH * NQTOK / TBM, D_MODEL / TBN), 256, 0, stream>>>(
        aoh, aol, woh, wol, bo, out);
  } else {
    float* Qws = (float*)d_ws;
    float* Kws = Qws + mat;
    float* Vws = Kws + mat;
    float* AOws = Qws;
    const dim3 gg(BATCH * NQTOK / GBM, D_MODEL / GBN);
    proj_gemm<<<gg, 256, 0, stream>>>(queries, wq, bq, Qws);
    proj_gemm<<<gg, 256, 0, stream>>>(keys,    wk, bk, Kws);
    proj_gemm<<<gg, 256, 0, stream>>>(values,  wv, bv, Vws);
    local_attn<<<dim3(BATCH * N_HEADS * (NQTOK / QB)), 256, 0, stream>>>(Qws, Kws, Vws, AOws);
    proj_gemm<<<gg, 256, 0, stream>>>(AOws, wo, bo, out);
  }
}